// Round 1
// baseline (1268.342 us; speedup 1.0000x reference)
//
#include <hip/hip_runtime.h>
#include <stdint.h>

typedef __attribute__((ext_vector_type(8))) __bf16 bf16x8;
typedef __attribute__((ext_vector_type(4))) float f32x4;

#define BATCH 1024
#define DDIM 384
#define NOUT 768
#define KWIDE (DDIM * DDIM)   // 147456
#define KDEEP (2 * DDIM)      // 768
#define LDO (4 * DDIM)        // 1536 output row stride

#define BM 128
#define BN 128
#define BK 64
#define SPLITS 16

union P8 { __bf16 b[8]; uint4 u; };
union P4 { __bf16 b[4]; uint2 u; };

__device__ inline uint4 cvt8(float4 f0, float4 f1) {
    P8 p;
    p.b[0] = (__bf16)f0.x; p.b[1] = (__bf16)f0.y;
    p.b[2] = (__bf16)f0.z; p.b[3] = (__bf16)f0.w;
    p.b[4] = (__bf16)f1.x; p.b[5] = (__bf16)f1.y;
    p.b[6] = (__bf16)f1.z; p.b[7] = (__bf16)f1.w;
    return p.u;
}

__device__ inline uint4 cvt8s(float4 f0, float4 f1, float s) {
    P8 p;
    p.b[0] = (__bf16)(s * f0.x); p.b[1] = (__bf16)(s * f0.y);
    p.b[2] = (__bf16)(s * f0.z); p.b[3] = (__bf16)(s * f0.w);
    p.b[4] = (__bf16)(s * f1.x); p.b[5] = (__bf16)(s * f1.y);
    p.b[6] = (__bf16)(s * f1.z); p.b[7] = (__bf16)(s * f1.w);
    return p.u;
}

// ---------------------------------------------------------------------------
// Convert W_L2 and W_L fp32 -> bf16 into workspace (bf16 W_L2 = 226MB < LLC).
// ---------------------------------------------------------------------------
__global__ __launch_bounds__(256) void convert_weights(
    const float* __restrict__ w2, const float* __restrict__ wl,
    __bf16* __restrict__ o2, __bf16* __restrict__ ol) {
    const size_t n2 = (size_t)NOUT * KWIDE / 4;
    const size_t nl = (size_t)NOUT * KDEEP / 4;
    const size_t stride = (size_t)gridDim.x * blockDim.x;
    for (size_t v = (size_t)blockIdx.x * blockDim.x + threadIdx.x; v < n2; v += stride) {
        float4 f = ((const float4*)w2)[v];
        P4 p;
        p.b[0] = (__bf16)f.x; p.b[1] = (__bf16)f.y;
        p.b[2] = (__bf16)f.z; p.b[3] = (__bf16)f.w;
        ((uint2*)o2)[v] = p.u;
    }
    for (size_t v = (size_t)blockIdx.x * blockDim.x + threadIdx.x; v < nl; v += stride) {
        float4 f = ((const float4*)wl)[v];
        P4 p;
        p.b[0] = (__bf16)f.x; p.b[1] = (__bf16)f.y;
        p.b[2] = (__bf16)f.z; p.b[3] = (__bf16)f.w;
        ((uint2*)ol)[v] = p.u;
    }
}

// ---------------------------------------------------------------------------
// Bias init: out[b, c] = c < 768 ? b_L[c] : b_L2[c-768]. GEMMs atomicAdd onto it.
// ---------------------------------------------------------------------------
__global__ __launch_bounds__(256) void init_bias(
    const float* __restrict__ bl, const float* __restrict__ bl2,
    float* __restrict__ out) {
    int idx = blockIdx.x * 256 + threadIdx.x;
    if (idx < BATCH * LDO) {
        int c = idx % LDO;
        out[idx] = (c < NOUT) ? bl[c] : bl2[c - NOUT];
    }
}

// ---------------------------------------------------------------------------
// Fused GEMM: C[m,n] (+)= sum_k A[m,k] * W[n,k]   (W row-major [N, Ktot])
//   WIDE:  A[m,k] = hs[m, k/384] * ht[m, k%384]   (on-the-fly outer product)
//   !WIDE: A[m,k] = k<384 ? hs[m,k] : ht[m,k-384] (concat)
//   WBF16: W is pre-converted bf16 in ws; else fp32 converted in-register.
// 128x128 tile, BK=64, 4 waves of 64x64, mfma_f32_16x16x32_bf16.
// Split-K over blockIdx.z, partials accumulated with atomicAdd (bias pre-set).
// ---------------------------------------------------------------------------
template <bool WBF16, bool WIDE>
__global__ __launch_bounds__(256) void gemm_fused(
    const float* __restrict__ hs, const float* __restrict__ ht,
    const void* __restrict__ wv, float* __restrict__ out,
    int Ktot, int kchunk, int coloff) {

    __shared__ __bf16 As[BM * BK];
    __shared__ __bf16 Bs[BN * BK];

    const int tid  = threadIdx.x;
    const int lane = tid & 63;
    const int wave = tid >> 6;
    const int quad = lane >> 4;
    const int lrow = lane & 15;
    const int wm   = (wave >> 1) * 64;
    const int wn   = (wave & 1) * 64;
    const int m0   = blockIdx.x * BM;
    const int n0   = blockIdx.y * BN;
    const int kb   = blockIdx.z * kchunk;
    const int ke   = kb + kchunk;

    // staging map: 8 threads per row-slot; thread handles rows ar+32q, cols [ac, ac+8)
    const int ar = tid >> 3;        // 0..31
    const int ac = (tid & 7) * 8;   // 0,8,...,56

    f32x4 acc[4][4] = {};

    for (int k0 = kb; k0 < ke; k0 += BK) {
        // ---- stage B tile: W[n0..n0+128, k0..k0+64] -> Bs (bf16) ----
        if (WBF16) {
            const __bf16* w = (const __bf16*)wv;
#pragma unroll
            for (int q = 0; q < 4; ++q) {
                int r = ar + 32 * q;
                uint4 v = *(const uint4*)(w + (size_t)(n0 + r) * Ktot + k0 + ac);
                *(uint4*)&Bs[r * BK + ac] = v;
            }
        } else {
            const float* w = (const float*)wv;
#pragma unroll
            for (int q = 0; q < 4; ++q) {
                int r = ar + 32 * q;
                const float* src = w + (size_t)(n0 + r) * Ktot + k0 + ac;
                float4 f0 = *(const float4*)src;
                float4 f1 = *(const float4*)(src + 4);
                *(uint4*)&Bs[r * BK + ac] = cvt8(f0, f1);
            }
        }
        // ---- generate A tile -> As (bf16) ----
        if (WIDE) {
            const int i  = k0 / DDIM;      // block-uniform (BK | 384)
            const int j0 = k0 % DDIM;
#pragma unroll
            for (int q = 0; q < 4; ++q) {
                int r = ar + 32 * q;
                float s = hs[(size_t)(m0 + r) * DDIM + i];
                const float* src = ht + (size_t)(m0 + r) * DDIM + j0 + ac;
                float4 f0 = *(const float4*)src;
                float4 f1 = *(const float4*)(src + 4);
                *(uint4*)&As[r * BK + ac] = cvt8s(f0, f1, s);
            }
        } else {
            int k = k0 + ac;               // 8-col group never straddles 384
            const float* base = (k < DDIM) ? hs : ht;
            int kk = (k < DDIM) ? k : k - DDIM;
#pragma unroll
            for (int q = 0; q < 4; ++q) {
                int r = ar + 32 * q;
                const float* src = base + (size_t)(m0 + r) * DDIM + kk;
                float4 f0 = *(const float4*)src;
                float4 f1 = *(const float4*)(src + 4);
                *(uint4*)&As[r * BK + ac] = cvt8(f0, f1);
            }
        }
        __syncthreads();
        // ---- compute: 2 k-steps x 16 MFMA ----
#pragma unroll
        for (int s = 0; s < 2; ++s) {
            bf16x8 af[4], bfr[4];
#pragma unroll
            for (int t = 0; t < 4; ++t)
                af[t] = *(const bf16x8*)&As[(wm + t * 16 + lrow) * BK + s * 32 + quad * 8];
#pragma unroll
            for (int t = 0; t < 4; ++t)
                bfr[t] = *(const bf16x8*)&Bs[(wn + t * 16 + lrow) * BK + s * 32 + quad * 8];
#pragma unroll
            for (int i2 = 0; i2 < 4; ++i2)
#pragma unroll
                for (int j2 = 0; j2 < 4; ++j2)
                    acc[i2][j2] = __builtin_amdgcn_mfma_f32_16x16x32_bf16(
                        af[i2], bfr[j2], acc[i2][j2], 0, 0, 0);
        }
        __syncthreads();
    }

    // ---- epilogue: C/D layout col=lane&15, row=quad*4+reg ----
#pragma unroll
    for (int i2 = 0; i2 < 4; ++i2) {
#pragma unroll
        for (int j2 = 0; j2 < 4; ++j2) {
            int gr = m0 + wm + i2 * 16 + quad * 4;
            int gc = coloff + n0 + wn + j2 * 16 + lrow;
#pragma unroll
            for (int r = 0; r < 4; ++r)
                atomicAdd(&out[(size_t)(gr + r) * LDO + gc], acc[i2][j2][r]);
        }
    }
}

extern "C" void kernel_launch(void* const* d_in, const int* in_sizes, int n_in,
                              void* d_out, int out_size, void* d_ws, size_t ws_size,
                              hipStream_t stream) {
    const float* hs  = (const float*)d_in[0];
    const float* ht  = (const float*)d_in[1];
    const float* wl  = (const float*)d_in[2];
    const float* bl  = (const float*)d_in[3];
    const float* w2  = (const float*)d_in[4];
    const float* bl2 = (const float*)d_in[5];
    float* out = (float*)d_out;

    const size_t n2   = (size_t)NOUT * KWIDE;
    const size_t nl   = (size_t)NOUT * KDEEP;
    const size_t need = (n2 + nl) * 2;  // bytes of bf16
    const bool bf16path = (ws_size >= need);

    dim3 blk(256);
    init_bias<<<(BATCH * LDO + 255) / 256, blk, 0, stream>>>(bl, bl2, out);

    if (bf16path) {
        __bf16* o2 = (__bf16*)d_ws;
        __bf16* ol = o2 + n2;
        convert_weights<<<4096, blk, 0, stream>>>(w2, wl, o2, ol);
        gemm_fused<true, false><<<dim3(8, 6, 1), blk, 0, stream>>>(
            hs, ht, (const void*)ol, out, KDEEP, KDEEP, 0);
        gemm_fused<true, true><<<dim3(8, 6, SPLITS), blk, 0, stream>>>(
            hs, ht, (const void*)o2, out, KWIDE, KWIDE / SPLITS, NOUT);
    } else {
        gemm_fused<false, false><<<dim3(8, 6, 1), blk, 0, stream>>>(
            hs, ht, (const void*)wl, out, KDEEP, KDEEP, 0);
        gemm_fused<false, true><<<dim3(8, 6, SPLITS), blk, 0, stream>>>(
            hs, ht, (const void*)w2, out, KWIDE, KWIDE / SPLITS, NOUT);
    }
}

// Round 2
// 1132.718 us; speedup vs baseline: 1.1197x; 1.1197x over previous
//
#include <hip/hip_runtime.h>
#include <stdint.h>

typedef __attribute__((ext_vector_type(8))) __bf16 bf16x8;
typedef __attribute__((ext_vector_type(4))) float f32x4;

#define BATCH 1024
#define DDIM 384
#define NOUT 768
#define KWIDE (DDIM * DDIM)   // 147456
#define KDEEP (2 * DDIM)      // 768
#define LDO (4 * DDIM)        // 1536 output row stride

#define BM 128
#define BN 128
#define BK 64
#define LDSK 72               // padded LDS stride: 144B = 36 banks -> conflict-free b128
#define SPLITS 32

union P8 { __bf16 b[8]; uint4 u; };

__device__ inline uint4 cvt8(float4 f0, float4 f1) {
    P8 p;
    p.b[0] = (__bf16)f0.x; p.b[1] = (__bf16)f0.y;
    p.b[2] = (__bf16)f0.z; p.b[3] = (__bf16)f0.w;
    p.b[4] = (__bf16)f1.x; p.b[5] = (__bf16)f1.y;
    p.b[6] = (__bf16)f1.z; p.b[7] = (__bf16)f1.w;
    return p.u;
}

__device__ inline uint4 cvt8s(float4 f0, float4 f1, float s) {
    P8 p;
    p.b[0] = (__bf16)(s * f0.x); p.b[1] = (__bf16)(s * f0.y);
    p.b[2] = (__bf16)(s * f0.z); p.b[3] = (__bf16)(s * f0.w);
    p.b[4] = (__bf16)(s * f1.x); p.b[5] = (__bf16)(s * f1.y);
    p.b[6] = (__bf16)(s * f1.z); p.b[7] = (__bf16)(s * f1.w);
    return p.u;
}

// ---------------------------------------------------------------------------
// Bias init: out[b, c] = c < 768 ? b_L[c] : b_L2[c-768]. GEMMs atomicAdd onto it.
// ---------------------------------------------------------------------------
__global__ __launch_bounds__(256) void init_bias(
    const float* __restrict__ bl, const float* __restrict__ bl2,
    float* __restrict__ out) {
    int idx = blockIdx.x * 256 + threadIdx.x;
    if (idx < BATCH * LDO) {
        int c = idx % LDO;
        out[idx] = (c < NOUT) ? bl[c] : bl2[c - NOUT];
    }
}

// ---------------------------------------------------------------------------
// Fused GEMM: C[m,n] (+)= sum_k A[m,k] * W[n,k]   (W row-major [N, Ktot], fp32)
//   WIDE:  A[m,k] = hs[m, k/384] * ht[m, k%384]   (on-the-fly outer product)
//   !WIDE: A[m,k] = k<384 ? hs[m,k] : ht[m,k-384] (concat)
// 128x128 tile, BK=64, 4 waves of 64x64, mfma_f32_16x16x32_bf16.
// Register-prefetch pipeline: k+1 global loads issued between the barriers so
// VMEM latency overlaps the MFMA block. LDS stride padded to 72 (no conflicts).
// Split-K over blockIdx.z; partials accumulated with atomicAdd (bias pre-set).
// ---------------------------------------------------------------------------
template <bool WIDE>
__global__ __launch_bounds__(256) void gemm_fused(
    const float* __restrict__ hs, const float* __restrict__ ht,
    const float* __restrict__ w, float* __restrict__ out,
    int Ktot, int kchunk, int coloff) {

    __shared__ __bf16 As[BM * LDSK];
    __shared__ __bf16 Bs[BN * LDSK];

    const int tid  = threadIdx.x;
    const int lane = tid & 63;
    const int wave = tid >> 6;
    const int quad = lane >> 4;
    const int lrow = lane & 15;
    const int wm   = (wave >> 1) * 64;
    const int wn   = (wave & 1) * 64;
    const int m0   = blockIdx.x * BM;
    const int n0   = blockIdx.y * BN;
    const int kb   = blockIdx.z * kchunk;
    const int ke   = kb + kchunk;

    // staging map: 8 threads per row-slot; thread handles rows ar+32q, cols [ac, ac+8)
    const int ar = tid >> 3;        // 0..31
    const int ac = (tid & 7) * 8;   // 0,8,...,56

    f32x4 acc[4][4] = {};

    // register prefetch buffers (fp32)
    float4 wb[4][2];   // B tile slice
    float4 ab[4][2];   // A source slice (ht rows or concat rows)
    float  sb[4];      // hs scalars (WIDE only)

    auto load_tile = [&](int k0) {
#pragma unroll
        for (int q = 0; q < 4; ++q) {
            const float* bsrc = w + (size_t)(n0 + ar + 32 * q) * Ktot + k0 + ac;
            wb[q][0] = *(const float4*)bsrc;
            wb[q][1] = *(const float4*)(bsrc + 4);
        }
        if (WIDE) {
            const int i  = k0 / DDIM;     // block-uniform (BK | 384)
            const int j0 = k0 % DDIM;
#pragma unroll
            for (int q = 0; q < 4; ++q) {
                const size_t r = (size_t)(m0 + ar + 32 * q) * DDIM;
                sb[q] = hs[r + i];
                const float* asrc = ht + r + j0 + ac;
                ab[q][0] = *(const float4*)asrc;
                ab[q][1] = *(const float4*)(asrc + 4);
            }
        } else {
            int k = k0 + ac;              // 8-col group never straddles 384
            const float* base = (k < DDIM) ? hs : ht;
            int kk = (k < DDIM) ? k : k - DDIM;
#pragma unroll
            for (int q = 0; q < 4; ++q) {
                const float* asrc = base + (size_t)(m0 + ar + 32 * q) * DDIM + kk;
                ab[q][0] = *(const float4*)asrc;
                ab[q][1] = *(const float4*)(asrc + 4);
            }
        }
    };

    auto store_tile = [&]() {
#pragma unroll
        for (int q = 0; q < 4; ++q) {
            int r = ar + 32 * q;
            *(uint4*)&Bs[r * LDSK + ac] = cvt8(wb[q][0], wb[q][1]);
            *(uint4*)&As[r * LDSK + ac] =
                WIDE ? cvt8s(ab[q][0], ab[q][1], sb[q]) : cvt8(ab[q][0], ab[q][1]);
        }
    };

    load_tile(kb);

    for (int k0 = kb; k0 < ke; k0 += BK) {
        store_tile();
        __syncthreads();
        if (k0 + BK < ke) load_tile(k0 + BK);   // overlaps MFMA below
        // ---- compute: 2 k-steps x 16 MFMA ----
#pragma unroll
        for (int s = 0; s < 2; ++s) {
            bf16x8 af[4], bfr[4];
#pragma unroll
            for (int t = 0; t < 4; ++t)
                af[t] = *(const bf16x8*)&As[(wm + t * 16 + lrow) * LDSK + s * 32 + quad * 8];
#pragma unroll
            for (int t = 0; t < 4; ++t)
                bfr[t] = *(const bf16x8*)&Bs[(wn + t * 16 + lrow) * LDSK + s * 32 + quad * 8];
#pragma unroll
            for (int i2 = 0; i2 < 4; ++i2)
#pragma unroll
                for (int j2 = 0; j2 < 4; ++j2)
                    acc[i2][j2] = __builtin_amdgcn_mfma_f32_16x16x32_bf16(
                        af[i2], bfr[j2], acc[i2][j2], 0, 0, 0);
        }
        __syncthreads();
    }

    // ---- epilogue: C/D layout col=lane&15, row=quad*4+reg ----
#pragma unroll
    for (int i2 = 0; i2 < 4; ++i2) {
#pragma unroll
        for (int j2 = 0; j2 < 4; ++j2) {
            int gr = m0 + wm + i2 * 16 + quad * 4;
            int gc = coloff + n0 + wn + j2 * 16 + lrow;
#pragma unroll
            for (int r = 0; r < 4; ++r)
                atomicAdd(&out[(size_t)(gr + r) * LDO + gc], acc[i2][j2][r]);
        }
    }
}

extern "C" void kernel_launch(void* const* d_in, const int* in_sizes, int n_in,
                              void* d_out, int out_size, void* d_ws, size_t ws_size,
                              hipStream_t stream) {
    const float* hs  = (const float*)d_in[0];
    const float* ht  = (const float*)d_in[1];
    const float* wl  = (const float*)d_in[2];
    const float* bl  = (const float*)d_in[3];
    const float* w2  = (const float*)d_in[4];
    const float* bl2 = (const float*)d_in[5];
    float* out = (float*)d_out;

    dim3 blk(256);
    init_bias<<<(BATCH * LDO + 255) / 256, blk, 0, stream>>>(bl, bl2, out);

    // deep path: [1024,768] = concat(hs,ht) @ W_L^T  (K=768, no split)
    gemm_fused<false><<<dim3(8, 6, 1), blk, 0, stream>>>(
        hs, ht, wl, out, KDEEP, KDEEP, 0);
    // wide path: [1024,768] = (hs outer ht) @ W_L2^T  (K=147456, split-K 32)
    gemm_fused<true><<<dim3(8, 6, SPLITS), blk, 0, stream>>>(
        hs, ht, w2, out, KWIDE, KWIDE / SPLITS, NOUT);
}